// Round 3
// baseline (121.901 us; speedup 1.0000x reference)
//
#include <hip/hip_runtime.h>
#include <hip/hip_cooperative_groups.h>

namespace cg = cooperative_groups;

#define D_SAMPLE 256
#define KCLIENTS 64
#define NH 128     // hidden dim
#define STAGE_K 6  // client rows staged to LDS during phase 1
#define BLOCK 256

__global__ __launch_bounds__(BLOCK, 4)
void lf_fused_kernel(const float* __restrict__ client,
                     const float* __restrict__ globalt,
                     const float* __restrict__ W1,
                     const float* __restrict__ b1,
                     const float* __restrict__ W2,
                     const float* __restrict__ b2,
                     float* __restrict__ scores,   // d_ws, 64 floats
                     float* __restrict__ out,
                     int D, int D4) {
    __shared__ float4 stage[STAGE_K][BLOCK];   // 24 KB
    __shared__ float  w[KCLIENTS];
    __shared__ float  ph[2][NH];
    __shared__ float  red[2];
    __shared__ float  attn[2 * D_SAMPLE];      // [client samples | global samples]

    const int t = threadIdx.x;
    const int b = blockIdx.x;
    const float4* __restrict__ c4 = (const float4*)client;
    const float4* __restrict__ g4 = (const float4*)globalt;
    float4* __restrict__ o4 = (float4*)out;

    const int d = b * BLOCK + t;   // this thread's float4 index in [0, D4)

    // ================= Phase 1 =================
    if (b < KCLIENTS) {
        // ---- score for client k = b ----
        const int k = b;
        attn[t]            = client[(size_t)k * D + t];   // t in [0,256)
        attn[D_SAMPLE + t] = globalt[t];
        __syncthreads();

        const int q = t >> 7;        // i-half: 0 -> client samples, 1 -> global samples
        const int j = t & (NH - 1);  // hidden unit
        const float* __restrict__ w1p = W1 + (size_t)(q * D_SAMPLE) * NH + j;
        const float* __restrict__ xp  = attn + q * D_SAMPLE;

        float acc = 0.0f;
#pragma unroll 8
        for (int i = 0; i < D_SAMPLE; ++i)
            acc = fmaf(xp[i], w1p[(size_t)i * NH], acc);
        ph[q][j] = acc;
        __syncthreads();

        if (t < NH) {
            float h = b1[j] + ph[0][j] + ph[1][j];
            h = fmaxf(h, 0.0f);
            float v = h * W2[j];
#pragma unroll
            for (int off = 32; off > 0; off >>= 1)
                v += __shfl_down(v, off, 64);
            if ((t & 63) == 0) red[t >> 6] = v;
        }
        __syncthreads();
        if (t == 0) {
            scores[k] = red[0] + red[1] + b2[0];
            __threadfence();   // device-scope visibility before grid sync
        }
        __syncthreads();
    }

    // ---- all blocks: stage first STAGE_K client rows for their d-range ----
#pragma unroll
    for (int k = 0; k < STAGE_K; ++k) {
        float4 v = make_float4(0.f, 0.f, 0.f, 0.f);
        if (d < D4) v = c4[(size_t)k * D4 + d];
        stage[k][t] = v;
    }

    cg::this_grid().sync();

    // ================= Phase 2 =================
    // per-block softmax over the 64 scores (L2-hot)
    if (t < KCLIENTS) {
        float s = scores[t];
        float m = s;
#pragma unroll
        for (int off = 32; off > 0; off >>= 1)
            m = fmaxf(m, __shfl_xor(m, off, 64));
        float e = __expf(s - m);
        float sum = e;
#pragma unroll
        for (int off = 32; off > 0; off >>= 1)
            sum += __shfl_xor(sum, off, 64);
        w[t] = e / sum;
    }
    __syncthreads();

    if (d < D4) {
        float4 acc = make_float4(0.f, 0.f, 0.f, 0.f);
#pragma unroll
        for (int k = 0; k < STAGE_K; ++k) {
            const float wk = w[k];
            const float4 c = stage[k][t];
            acc.x = fmaf(wk, c.x, acc.x);
            acc.y = fmaf(wk, c.y, acc.y);
            acc.z = fmaf(wk, c.z, acc.z);
            acc.w = fmaf(wk, c.w, acc.w);
        }
#pragma unroll 4
        for (int k = STAGE_K; k < KCLIENTS; ++k) {
            const float wk = w[k];
            const float4 c = c4[(size_t)k * D4 + d];
            acc.x = fmaf(wk, c.x, acc.x);
            acc.y = fmaf(wk, c.y, acc.y);
            acc.z = fmaf(wk, c.z, acc.z);
            acc.w = fmaf(wk, c.w, acc.w);
        }
        const float4 g = g4[d];
        float4 r;
        r.x = 0.5f * g.x + 0.5f * acc.x;
        r.y = 0.5f * g.y + 0.5f * acc.y;
        r.z = 0.5f * g.z + 0.5f * acc.z;
        r.w = 0.5f * g.w + 0.5f * acc.w;
        o4[d] = r;
    }
}

extern "C" void kernel_launch(void* const* d_in, const int* in_sizes, int n_in,
                              void* d_out, int out_size, void* d_ws, size_t ws_size,
                              hipStream_t stream) {
    const float* client  = (const float*)d_in[0];  // [64, D]
    const float* globalt = (const float*)d_in[1];  // [1, D]
    const float* W1      = (const float*)d_in[2];  // [512, 128]
    const float* b1      = (const float*)d_in[3];  // [128]
    const float* W2      = (const float*)d_in[4];  // [128, 1]
    const float* b2      = (const float*)d_in[5];  // [1]
    float* out = (float*)d_out;                    // [1, D]

    int D  = in_sizes[0] / KCLIENTS;               // 1,000,000
    int D4 = D / 4;                                // 250,000

    float* scores = (float*)d_ws;                  // 64 floats

    int grid = (D4 + BLOCK - 1) / BLOCK;           // 977 blocks (<= 1024 co-resident)

    void* args[] = {
        (void*)&client, (void*)&globalt, (void*)&W1, (void*)&b1,
        (void*)&W2, (void*)&b2, (void*)&scores, (void*)&out,
        (void*)&D, (void*)&D4
    };
    hipLaunchCooperativeKernel((const void*)lf_fused_kernel,
                               dim3(grid), dim3(BLOCK),
                               args, 0, stream);
}